// Round 8
// baseline (139.488 us; speedup 1.0000x reference)
//
#include <hip/hip_runtime.h>
#include <hip/hip_bf16.h>

#define BATCH 64
#define HW    4096
#define PT    128      // positions per k2 tile
#define NS    32       // HW / PT
#define FT_ST 136      // featT / es_t row stride in u16 (128 pos + 8 pad)

// LDS map for k2 (u16 units):
#define FT_BASE  0       // featT [80][136]          = 10880 u16
#define EST_BASE 10880   // es_t  [16][136]          = 2176 u16 (only rows 0..3 written)
#define PR_BASE  13056   // poolred 1280 f32         = 2560 u16
#define RED_BASE 15616   // redf 16 f32 + red2f 16 f32 = 64 u16
#define SMEM_TOT 15680   // 31360 B -> 4 blocks/CU with 128 VGPR cap

typedef unsigned int u32;
typedef unsigned short u16;
typedef __attribute__((ext_vector_type(8))) short bf16x8;
typedef __attribute__((ext_vector_type(4))) float f32x4;

__device__ __forceinline__ float bf2f(u16 h) { return __uint_as_float(((u32)h) << 16); }
__device__ __forceinline__ u32 f2bf(float x) {
  u32 b = __float_as_uint(x);
  return (b + 0x7fffu + ((b >> 16) & 1u)) >> 16;
}
__device__ __forceinline__ u32 pkbf(float lo, float hi) { return f2bf(lo) | (f2bf(hi) << 16); }

template<bool F32>
__device__ __forceinline__ float ld(const void* p, size_t i) {
  if (F32) return ((const float*)p)[i];
  return bf2f(((const u16*)p)[i]);
}
template<bool F32>
__device__ __forceinline__ void st(void* p, size_t i, float v) {
  if (F32) ((float*)p)[i] = v;
  else     ((__hip_bfloat16*)p)[i] = __float2bfloat16(v);
}

// Per-wave dtype sniff (block-uniform; same 128B every wave -> L2 broadcast).
__device__ __forceinline__ bool detect_f32(const u16* __restrict__ image) {
  u16 h = image[(threadIdx.x & 63) * 2];
  u32 e = (h >> 7) & 0xFFu;
  unsigned long long m = __ballot(e >= 0x86u);
  return __popcll(m) >= 8;
}

// ---------------- K1: q = state@Wq+bq; weffbt (bf16 [n][104] zero-padded); cb ----------------
template<bool F32>
__device__ void k1_body(const void* state1, const void* state2, const void* Wq, const void* bq,
                        const void* Wk, const void* bk, u16* weffbt, float* cb,
                        float* stt, float* qp, float* q) {
  const int b = blockIdx.x, tid = threadIdx.x;
  for (int i = tid; i < 512; i += 256) {
    stt[i]       = ld<F32>(state1, (size_t)b * 512 + i);
    stt[512 + i] = ld<F32>(state2, (size_t)b * 512 + i);
  }
  u32* wz = (u32*)(weffbt + (size_t)b * 1664);
  for (int i = tid; i < 832; i += 256) wz[i] = 0u;
  __syncthreads();
  {
    const int j = tid & 63, g = tid >> 6, i0 = g * 256;
    float a = 0.f;
#pragma unroll 8
    for (int i = 0; i < 256; ++i) a += stt[i0 + i] * ld<F32>(Wq, (size_t)(i0 + i) * 64 + j);
    qp[g * 64 + j] = a;
  }
  __syncthreads();
  if (tid < 64) q[tid] = qp[tid] + qp[64 + tid] + qp[128 + tid] + qp[192 + tid] + ld<F32>(bq, tid);
  __syncthreads();
  for (int t = tid; t < 320; t += 256) {
    const int c = t >> 2, n = t & 3;
    float a = 0.f;
#pragma unroll
    for (int d = 0; d < 16; ++d) a += ld<F32>(Wk, (size_t)c * 64 + n * 16 + d) * q[n * 16 + d];
    weffbt[(size_t)b * 1664 + n * 104 + c] = (u16)f2bf(a);
  }
  if (tid < 4) {
    float a = 0.f;
#pragma unroll
    for (int d = 0; d < 16; ++d) a += ld<F32>(bk, tid * 16 + d) * q[tid * 16 + d];
    cb[b * 4 + tid] = a;
  }
}

__global__ __launch_bounds__(256) void k1_prep(
    const void* image, const void* state1, const void* state2, const void* Wq, const void* bq,
    const void* Wk, const void* bk, u16* weffbt, float* cb) {
  __shared__ float stt[1024];
  __shared__ float qp[256];
  __shared__ float q[64];
  if (detect_f32((const u16*)image))
       k1_body<true >(state1, state2, Wq, bq, Wk, bk, weffbt, cb, stt, qp, q);
  else k1_body<false>(state1, state2, Wq, bq, Wk, bk, weffbt, cb, stt, qp, q);
}

// ---------------- K2: global-sourced MFMA score + local softmax + MFMA pooling ----------------
__global__ __launch_bounds__(256, 4) void k2_main(
    const void* __restrict__ image, const void* __restrict__ basis,
    const float* __restrict__ cb, const u16* __restrict__ weffbt,
    u16* __restrict__ e_buf, float* __restrict__ m_blk, float* __restrict__ sum_blk,
    float* __restrict__ fpool_part) {
  __shared__ __align__(16) u16 smem[SMEM_TOT];
  float* redf  = (float*)(smem + RED_BASE);
  float* red2f = (float*)(smem + RED_BASE + 32);

  const int tid = threadIdx.x;
  const int b = blockIdx.x & 63, s = blockIdx.x >> 6;
  const int bs = b * NS + s;
  const int wave = tid >> 6, lane = tid & 63;
  const int m = lane & 15, q = lane >> 4;
  const bool isf32 = detect_f32((const u16*)image);

  // ---- stage featT (ch-major) only ----
  if (isf32) {
    const float4* img4 = (const float4*)image + ((size_t)(b * HW + s * PT)) * 16;
#pragma unroll
    for (int i = 0; i < 4; ++i) {
      const int fidx = i * 256 + tid;
      const int pq = fidx >> 4, c4 = fidx & 15;
      float4 v0 = img4[(pq * 2) * 16 + c4];
      float4 v1 = img4[(pq * 2 + 1) * 16 + c4];
      *(u32*)&smem[FT_BASE + (c4 * 4 + 0) * FT_ST + pq * 2] = pkbf(v0.x, v1.x);
      *(u32*)&smem[FT_BASE + (c4 * 4 + 1) * FT_ST + pq * 2] = pkbf(v0.y, v1.y);
      *(u32*)&smem[FT_BASE + (c4 * 4 + 2) * FT_ST + pq * 2] = pkbf(v0.z, v1.z);
      *(u32*)&smem[FT_BASE + (c4 * 4 + 3) * FT_ST + pq * 2] = pkbf(v0.w, v1.w);
    }
    const float4* bas4 = (const float4*)basis + (size_t)(s * PT) * 4;
    {
      const int pq = tid >> 2, c4 = tid & 3;
      float4 v0 = bas4[(pq * 2) * 4 + c4];
      float4 v1 = bas4[(pq * 2 + 1) * 4 + c4];
      *(u32*)&smem[FT_BASE + (64 + c4 * 4 + 0) * FT_ST + pq * 2] = pkbf(v0.x, v1.x);
      *(u32*)&smem[FT_BASE + (64 + c4 * 4 + 1) * FT_ST + pq * 2] = pkbf(v0.y, v1.y);
      *(u32*)&smem[FT_BASE + (64 + c4 * 4 + 2) * FT_ST + pq * 2] = pkbf(v0.z, v1.z);
      *(u32*)&smem[FT_BASE + (64 + c4 * 4 + 3) * FT_ST + pq * 2] = pkbf(v0.w, v1.w);
    }
  } else {
    const uint4* img4 = (const uint4*)image + ((size_t)(b * HW + s * PT)) * 4;
    {
      const int pq = tid >> 2, c8 = tid & 3;
      uint4 u0 = img4[(pq * 2) * 4 + c8];
      uint4 u1 = img4[(pq * 2 + 1) * 4 + c8];
      const u32 w0[4] = {u0.x, u0.y, u0.z, u0.w};
      const u32 w1[4] = {u1.x, u1.y, u1.z, u1.w};
#pragma unroll
      for (int k = 0; k < 4; ++k) {
        *(u32*)&smem[FT_BASE + (c8 * 8 + 2 * k) * FT_ST + pq * 2]     = (w0[k] & 0xffffu) | (w1[k] << 16);
        *(u32*)&smem[FT_BASE + (c8 * 8 + 2 * k + 1) * FT_ST + pq * 2] = (w0[k] >> 16) | (w1[k] & 0xffff0000u);
      }
    }
    const uint4* bas4 = (const uint4*)basis + (size_t)(s * PT) * 2;
    if (tid < 128) {
      const int pq = tid >> 1, c8 = tid & 1;
      uint4 u0 = bas4[(pq * 2) * 2 + c8];
      uint4 u1 = bas4[(pq * 2 + 1) * 2 + c8];
      const u32 w0[4] = {u0.x, u0.y, u0.z, u0.w};
      const u32 w1[4] = {u1.x, u1.y, u1.z, u1.w};
#pragma unroll
      for (int k = 0; k < 4; ++k) {
        *(u32*)&smem[FT_BASE + (64 + c8 * 8 + 2 * k) * FT_ST + pq * 2]     = (w0[k] & 0xffffu) | (w1[k] << 16);
        *(u32*)&smem[FT_BASE + (64 + c8 * 8 + 2 * k + 1) * FT_ST + pq * 2] = (w0[k] >> 16) | (w1[k] & 0xffff0000u);
      }
    }
  }

  // ---- score MFMA, operands straight from global (no barrier needed) ----
  // B-frags: weffbt[b] row m (head), k = s3*32 + q*8 (zero-padded cols 80..103)
  bf16x8 bfr[3];
  {
    const u16* wrow = weffbt + (size_t)b * 1664 + m * 104;
#pragma unroll
    for (int s3 = 0; s3 < 3; ++s3) bfr[s3] = *(const bf16x8*)&wrow[s3 * 32 + q * 8];
  }
  f32x4 accS[2];
  {
    const float ci = (m < 4) ? cb[b * 4 + m] : 0.f;
#pragma unroll
    for (int t = 0; t < 2; ++t) { accS[t][0] = ci; accS[t][1] = ci; accS[t][2] = ci; accS[t][3] = ci; }
#pragma unroll
    for (int t = 0; t < 2; ++t) {
      const int p = s * PT + (wave * 2 + t) * 16 + m;   // global position (A row)
#pragma unroll
      for (int s3 = 0; s3 < 3; ++s3) {
        bf16x8 a;
        if (isf32) {
          float4 v0, v1;
          if (s3 < 2) {
            const float4* ip = (const float4*)image + ((size_t)b * HW + p) * 16 + s3 * 8 + q * 2;
            v0 = ip[0]; v1 = ip[1];
          } else if (q < 2) {
            const float4* bp = (const float4*)basis + (size_t)p * 4 + q * 2;
            v0 = bp[0]; v1 = bp[1];
          } else { v0 = make_float4(0, 0, 0, 0); v1 = v0; }
          u32 aw[4] = {pkbf(v0.x, v0.y), pkbf(v0.z, v0.w), pkbf(v1.x, v1.y), pkbf(v1.z, v1.w)};
          a = *(const bf16x8*)aw;
        } else {
          if (s3 < 2) a = *(const bf16x8*)&((const u16*)image)[((size_t)b * HW + p) * 64 + s3 * 32 + q * 8];
          else if (q < 2) a = *(const bf16x8*)&((const u16*)basis)[(size_t)p * 16 + q * 8];
          else { u32 z[4] = {0, 0, 0, 0}; a = *(const bf16x8*)z; }
        }
        accS[t] = __builtin_amdgcn_mfma_f32_16x16x32_bf16(a, bfr[s3], accS[t], 0, 0, 0);
      }
    }
  }
  // wave max per head col m (reduce over q via xor16/32)
  {
    float mx = accS[0][0];
#pragma unroll
    for (int t = 0; t < 2; ++t)
#pragma unroll
      for (int r = 0; r < 4; ++r) mx = fmaxf(mx, accS[t][r]);
    mx = fmaxf(mx, __shfl_xor(mx, 16, 64));
    mx = fmaxf(mx, __shfl_xor(mx, 32, 64));
    if (lane < 4) redf[wave * 4 + lane] = mx;
  }
  __syncthreads();   // B1: featT staged + redf ready

  // block max (register-resident, per lane)
  float bmv;
  {
    const int hh = m & 3;
    bmv = fmaxf(fmaxf(redf[hh], redf[4 + hh]), fmaxf(redf[8 + hh], redf[12 + hh]));
  }
  // exp (bf16-rounded), es_t write (lanes m<4), wave sum
  {
    float ss = 0.f;
#pragma unroll
    for (int t = 0; t < 2; ++t) {
      const int T = wave * 2 + t;
#pragma unroll
      for (int r = 0; r < 4; ++r) {
        float e = __expf(accS[t][r] - bmv);
        u32 eb = f2bf(e);
        ss += bf2f((u16)eb);
        if (m < 4) smem[EST_BASE + m * FT_ST + T * 16 + q * 4 + r] = (u16)eb;
      }
    }
    ss += __shfl_xor(ss, 16, 64);
    ss += __shfl_xor(ss, 32, 64);
    if (lane < 4) red2f[wave * 4 + lane] = ss;
  }
  __syncthreads();   // B2: es_t + red2f ready

  if (tid < 4) {
    const int hh = tid;
    m_blk[bs * 4 + hh] = fmaxf(fmaxf(redf[hh], redf[4 + hh]), fmaxf(redf[8 + hh], redf[12 + hh]));
    sum_blk[bs * 4 + hh] = red2f[hh] + red2f[4 + hh] + red2f[8 + hh] + red2f[12 + hh];
  }
  // e_buf copy (bf16), layout [b][n][p]
  {
    const int n = tid >> 6, pp = tid & 63;
    u32 v = *(const u32*)&smem[EST_BASE + n * FT_ST + pp * 2];
    ((u32*)e_buf)[((size_t)(b * 4 + n)) * 2048 + s * 64 + pp] = v;
  }
  // pool MFMA: D[16x80] = es_t[16x128] @ featT^T, K split across waves
  {
    bf16x8 ap = *(const bf16x8*)&smem[EST_BASE + m * FT_ST + wave * 32 + q * 8];
    f32x4 accP[5];
#pragma unroll
    for (int T = 0; T < 5; ++T) { accP[T][0] = 0; accP[T][1] = 0; accP[T][2] = 0; accP[T][3] = 0; }
#pragma unroll
    for (int T = 0; T < 5; ++T) {
      bf16x8 bp = *(const bf16x8*)&smem[FT_BASE + (T * 16 + m) * FT_ST + wave * 32 + q * 8];
      accP[T] = __builtin_amdgcn_mfma_f32_16x16x32_bf16(ap, bp, accP[T], 0, 0, 0);
    }
    if (lane < 16) {   // rows 0..3 (heads) live in lanes 0..15, regs 0..3
      float* pr = (float*)(smem + PR_BASE);
#pragma unroll
      for (int T = 0; T < 5; ++T)
#pragma unroll
        for (int r = 0; r < 4; ++r)
          pr[((wave * 5 + T) * 4 + r) * 16 + lane] = accP[T][r];
    }
  }
  __syncthreads();   // B3: poolred ready
  {
    const float* pr = (const float*)(smem + PR_BASE);
    for (int t = tid; t < 320; t += 256) {
      const int n = t / 80, c = t - n * 80;
      const int tile = c >> 4, cc = c & 15;
      float a = 0.f;
#pragma unroll
      for (int w = 0; w < 4; ++w) a += pr[((w * 5 + tile) * 4 + n) * 16 + cc];
      fpool_part[(size_t)bs * 320 + t] = a;
    }
  }
}

// ---------------- K34: escale; mean_attn; (s==0) pooled GEMV + extra ----------------
template<bool F32>
__device__ void k34_body(const float* m_blk, const float* sum_blk, const u16* e_buf,
                         const float* fpool_part, const void* Wv, const void* bv,
                         const void* extra, void* out, float* esc, float* fp) {
  const int tid = threadIdx.x;
  const int b = blockIdx.x & 63, s16 = blockIdx.x >> 6;
  if (tid < 4) {
    float M = -3.4e38f;
#pragma unroll
    for (int sp = 0; sp < NS; ++sp) M = fmaxf(M, m_blk[(b * NS + sp) * 4 + tid]);
    float den = 0.f;
#pragma unroll
    for (int sp = 0; sp < NS; ++sp)
      den += __expf(m_blk[(b * NS + sp) * 4 + tid] - M) * sum_blk[(b * NS + sp) * 4 + tid];
    float rd = 1.0f / den;
#pragma unroll
    for (int sp = 0; sp < NS; ++sp)
      esc[sp * 4 + tid] = __expf(m_blk[(b * NS + sp) * 4 + tid] - M) * rd;
  }
  __syncthreads();
  {
    const int gpos = s16 * 256 + tid;
    const int s32 = gpos >> 7;
    float mean = 0.f;
#pragma unroll
    for (int n = 0; n < 4; ++n)
      mean += bf2f(e_buf[(size_t)(b * 4 + n) * HW + gpos]) * esc[s32 * 4 + n];
    st<F32>(out, (size_t)BATCH * 320 + (size_t)b * HW + gpos, 0.25f * mean);
  }
  if (s16 == 0) {
    for (int idx = tid; idx < 320; idx += 256) {
      const int n2 = idx / 80;
      float a = 0.f;
#pragma unroll
      for (int sp = 0; sp < NS; ++sp)
        a += esc[sp * 4 + n2] * fpool_part[(size_t)(b * NS + sp) * 320 + idx];
      fp[idx] = a;
    }
    __syncthreads();
    if (tid < 64) {
      const int n = tid >> 4;
      float dot = 0.f;
#pragma unroll
      for (int c = 0; c < 80; ++c) dot += fp[n * 80 + c] * ld<F32>(Wv, (size_t)c * 64 + tid);
      st<F32>(out, (size_t)b * 320 + tid, dot + ld<F32>(bv, tid));
    }
    st<F32>(out, (size_t)b * 320 + 64 + tid, ld<F32>(extra, (size_t)b * 256 + tid));
  }
}

__global__ __launch_bounds__(256) void k34_out(
    const void* image, const float* m_blk, const float* sum_blk, const u16* e_buf,
    const float* fpool_part, const void* Wv, const void* bv, const void* extra, void* out) {
  __shared__ float esc[NS * 4];
  __shared__ float fp[320];
  if (detect_f32((const u16*)image))
       k34_body<true >(m_blk, sum_blk, e_buf, fpool_part, Wv, bv, extra, out, esc, fp);
  else k34_body<false>(m_blk, sum_blk, e_buf, fpool_part, Wv, bv, extra, out, esc, fp);
}

extern "C" void kernel_launch(void* const* d_in, const int* in_sizes, int n_in,
                              void* d_out, int out_size, void* d_ws, size_t ws_size,
                              hipStream_t stream) {
  (void)in_sizes; (void)n_in; (void)out_size; (void)ws_size;
  const void* image  = d_in[0];
  const void* state1 = d_in[1];
  const void* state2 = d_in[2];
  const void* extra  = d_in[3];
  const void* Wq = d_in[4];
  const void* bq = d_in[5];
  const void* Wk = d_in[6];
  const void* bk = d_in[7];
  const void* Wv = d_in[8];
  const void* bv = d_in[9];
  const void* basis = d_in[10];

  float* ws         = (float*)d_ws;
  float* cb         = ws;                    // 256
  float* m_blk      = ws + 256;              // 64*32*4 = 8192
  float* sum_blk    = ws + 8448;             // 8192
  float* fpool_part = ws + 16640;            // 2048*320 = 655360
  u16*   weffbt     = (u16*)(ws + 672000);   // 64*16*104 u16 = 106496
  u16*   e_buf      = (u16*)(ws + 725248);   // 64*4*4096 u16 (bf16)

  k1_prep<<<dim3(BATCH), dim3(256), 0, stream>>>(image, state1, state2, Wq, bq, Wk, bk, weffbt, cb);
  k2_main<<<dim3(BATCH * NS), dim3(256), 0, stream>>>(image, basis, cb, weffbt,
                                                      e_buf, m_blk, sum_blk, fpool_part);
  k34_out<<<dim3(BATCH * 16), dim3(256), 0, stream>>>(image, m_blk, sum_blk, e_buf,
                                                      fpool_part, Wv, bv, extra, d_out);
}

// Round 9
// 131.675 us; speedup vs baseline: 1.0593x; 1.0593x over previous
//
#include <hip/hip_runtime.h>
#include <hip/hip_bf16.h>

#define BATCH 64
#define HW    4096
#define PT    128      // positions per k2 tile
#define NS    32       // HW / PT
#define FT_ST 136      // featT / es_t row stride in u16 (128 pos + 8 pad)

// LDS map for k2 (u16 units):
#define FT_BASE  0       // featT [80][136] (pos-swizzled) = 10880 u16
#define EST_BASE 10880   // es_t  [16][136] (rows 0..3 written, 4..15 garbage-ok) = 2176
#define PR_BASE  13056   // poolred 1280 f32 = 2560 u16
#define RED_BASE 15616   // redf 16 f32 + red2f 16 f32 = 64 u16
#define SMEM_TOT 15680   // 31360 B

typedef unsigned int u32;
typedef unsigned short u16;
typedef __attribute__((ext_vector_type(8))) short bf16x8;
typedef __attribute__((ext_vector_type(4))) float f32x4;

__device__ __forceinline__ float bf2f(u16 h) { return __uint_as_float(((u32)h) << 16); }
__device__ __forceinline__ u32 f2bf(float x) {
  u32 b = __float_as_uint(x);
  return (b + 0x7fffu + ((b >> 16) & 1u)) >> 16;
}
__device__ __forceinline__ u32 pkbf(float lo, float hi) { return f2bf(lo) | (f2bf(hi) << 16); }

template<bool F32>
__device__ __forceinline__ float ld(const void* p, size_t i) {
  if (F32) return ((const float*)p)[i];
  return bf2f(((const u16*)p)[i]);
}
template<bool F32>
__device__ __forceinline__ void st(void* p, size_t i, float v) {
  if (F32) ((float*)p)[i] = v;
  else     ((__hip_bfloat16*)p)[i] = __float2bfloat16(v);
}

// Per-wave dtype sniff (block-uniform; same 128B every wave -> L2 broadcast).
__device__ __forceinline__ bool detect_f32(const u16* __restrict__ image) {
  u16 h = image[(threadIdx.x & 63) * 2];
  u32 e = (h >> 7) & 0xFFu;
  unsigned long long m = __ballot(e >= 0x86u);
  return __popcll(m) >= 8;
}

// position swizzle for featT row c: XOR pos bits 3..4 with (c>>3)&3
__device__ __forceinline__ int swz(int c) { return ((c >> 3) & 3) << 3; }

// ---------------- K1: q = state@Wq+bq; weffbt (bf16 [n][104] zero-padded); cb ----------------
template<bool F32>
__device__ void k1_body(const void* state1, const void* state2, const void* Wq, const void* bq,
                        const void* Wk, const void* bk, u16* weffbt, float* cb,
                        float* stt, float* qp, float* q) {
  const int b = blockIdx.x, tid = threadIdx.x;
  for (int i = tid; i < 512; i += 256) {
    stt[i]       = ld<F32>(state1, (size_t)b * 512 + i);
    stt[512 + i] = ld<F32>(state2, (size_t)b * 512 + i);
  }
  u32* wz = (u32*)(weffbt + (size_t)b * 1664);
  for (int i = tid; i < 832; i += 256) wz[i] = 0u;
  __syncthreads();
  {
    const int j = tid & 63, g = tid >> 6, i0 = g * 256;
    float a = 0.f;
#pragma unroll 8
    for (int i = 0; i < 256; ++i) a += stt[i0 + i] * ld<F32>(Wq, (size_t)(i0 + i) * 64 + j);
    qp[g * 64 + j] = a;
  }
  __syncthreads();
  if (tid < 64) q[tid] = qp[tid] + qp[64 + tid] + qp[128 + tid] + qp[192 + tid] + ld<F32>(bq, tid);
  __syncthreads();
  for (int t = tid; t < 320; t += 256) {
    const int c = t >> 2, n = t & 3;
    float a = 0.f;
#pragma unroll
    for (int d = 0; d < 16; ++d) a += ld<F32>(Wk, (size_t)c * 64 + n * 16 + d) * q[n * 16 + d];
    weffbt[(size_t)b * 1664 + n * 104 + c] = (u16)f2bf(a);
  }
  if (tid < 4) {
    float a = 0.f;
#pragma unroll
    for (int d = 0; d < 16; ++d) a += ld<F32>(bk, tid * 16 + d) * q[tid * 16 + d];
    cb[b * 4 + tid] = a;
  }
}

__global__ __launch_bounds__(256) void k1_prep(
    const void* image, const void* state1, const void* state2, const void* Wq, const void* bq,
    const void* Wk, const void* bk, u16* weffbt, float* cb) {
  __shared__ float stt[1024];
  __shared__ float qp[256];
  __shared__ float q[64];
  if (detect_f32((const u16*)image))
       k1_body<true >(state1, state2, Wq, bq, Wk, bk, weffbt, cb, stt, qp, q);
  else k1_body<false>(state1, state2, Wq, bq, Wk, bk, weffbt, cb, stt, qp, q);
}

// ---------------- K2: single-pack LDS staging; MFMA score (A via swizzled ds_read) + pool ----------------
__global__ __launch_bounds__(256, 4) void k2_main(
    const void* __restrict__ image, const void* __restrict__ basis,
    const float* __restrict__ cb, const u16* __restrict__ weffbt,
    u16* __restrict__ e_buf, float* __restrict__ m_blk, float* __restrict__ sum_blk,
    float* __restrict__ fpool_part) {
  __shared__ __align__(16) u16 smem[SMEM_TOT];
  float* redf  = (float*)(smem + RED_BASE);
  float* red2f = (float*)(smem + RED_BASE + 32);

  const int tid = threadIdx.x;
  const int b = blockIdx.x & 63, s = blockIdx.x >> 6;
  const int bs = b * NS + s;
  const int wave = tid >> 6, lane = tid & 63;
  const int m = lane & 15, q = lane >> 4;
  const bool isf32 = detect_f32((const u16*)image);

  // ---- stage featT (ch-major, pos-swizzled) — single pack per element ----
  if (isf32) {
    const float4* img4 = (const float4*)image + ((size_t)(b * HW + s * PT)) * 16;
#pragma unroll
    for (int i = 0; i < 4; ++i) {
      const int fidx = i * 256 + tid;
      const int pq = fidx >> 4, c4 = fidx & 15;
      const int ps = (pq * 2) ^ (((c4 >> 1) & 3) << 3);
      float4 v0 = img4[(pq * 2) * 16 + c4];
      float4 v1 = img4[(pq * 2 + 1) * 16 + c4];
      *(u32*)&smem[FT_BASE + (c4 * 4 + 0) * FT_ST + ps] = pkbf(v0.x, v1.x);
      *(u32*)&smem[FT_BASE + (c4 * 4 + 1) * FT_ST + ps] = pkbf(v0.y, v1.y);
      *(u32*)&smem[FT_BASE + (c4 * 4 + 2) * FT_ST + ps] = pkbf(v0.z, v1.z);
      *(u32*)&smem[FT_BASE + (c4 * 4 + 3) * FT_ST + ps] = pkbf(v0.w, v1.w);
    }
    const float4* bas4 = (const float4*)basis + (size_t)(s * PT) * 4;
    {
      const int pq = tid >> 2, c4 = tid & 3;
      const int ps = (pq * 2) ^ (((c4 >> 1) & 3) << 3);
      float4 v0 = bas4[(pq * 2) * 4 + c4];
      float4 v1 = bas4[(pq * 2 + 1) * 4 + c4];
      *(u32*)&smem[FT_BASE + (64 + c4 * 4 + 0) * FT_ST + ps] = pkbf(v0.x, v1.x);
      *(u32*)&smem[FT_BASE + (64 + c4 * 4 + 1) * FT_ST + ps] = pkbf(v0.y, v1.y);
      *(u32*)&smem[FT_BASE + (64 + c4 * 4 + 2) * FT_ST + ps] = pkbf(v0.z, v1.z);
      *(u32*)&smem[FT_BASE + (64 + c4 * 4 + 3) * FT_ST + ps] = pkbf(v0.w, v1.w);
    }
  } else {
    const uint4* img4 = (const uint4*)image + ((size_t)(b * HW + s * PT)) * 8;
#pragma unroll
    for (int i = 0; i < 2; ++i) {
      const int fidx = i * 256 + tid;              // 0..511: (pos-pair 0..63, c8 0..7)
      const int pq = fidx >> 3, c8 = fidx & 7;
      const int ps = (pq * 2) ^ ((c8 & 3) << 3);
      uint4 u0 = img4[(pq * 2) * 8 + c8];
      uint4 u1 = img4[(pq * 2 + 1) * 8 + c8];
      const u32 w0[4] = {u0.x, u0.y, u0.z, u0.w};
      const u32 w1[4] = {u1.x, u1.y, u1.z, u1.w};
#pragma unroll
      for (int k = 0; k < 4; ++k) {
        *(u32*)&smem[FT_BASE + (c8 * 8 + 2 * k) * FT_ST + ps]     = (w0[k] & 0xffffu) | (w1[k] << 16);
        *(u32*)&smem[FT_BASE + (c8 * 8 + 2 * k + 1) * FT_ST + ps] = (w0[k] >> 16) | (w1[k] & 0xffff0000u);
      }
    }
    const uint4* bas4 = (const uint4*)basis + (size_t)(s * PT) * 2;
    if (tid < 128) {
      const int pq = tid >> 1, c8 = tid & 1;
      const int ps = (pq * 2) ^ ((c8 & 3) << 3);
      uint4 u0 = bas4[(pq * 2) * 2 + c8];
      uint4 u1 = bas4[(pq * 2 + 1) * 2 + c8];
      const u32 w0[4] = {u0.x, u0.y, u0.z, u0.w};
      const u32 w1[4] = {u1.x, u1.y, u1.z, u1.w};
#pragma unroll
      for (int k = 0; k < 4; ++k) {
        *(u32*)&smem[FT_BASE + (64 + c8 * 8 + 2 * k) * FT_ST + ps]     = (w0[k] & 0xffffu) | (w1[k] << 16);
        *(u32*)&smem[FT_BASE + (64 + c8 * 8 + 2 * k + 1) * FT_ST + ps] = (w0[k] >> 16) | (w1[k] & 0xffff0000u);
      }
    }
  }
  // score B-frags from global (per-lane, L2-hot, no barrier dependency)
  bf16x8 bfr[3];
  {
    const u16* wrow = weffbt + (size_t)b * 1664 + m * 104;
#pragma unroll
    for (int s3 = 0; s3 < 3; ++s3) bfr[s3] = *(const bf16x8*)&wrow[s3 * 32 + q * 8];
  }
  __syncthreads();   // B1: featT staged

  // ---- score MFMA: A from featT via swizzled scalar ds_reads ----
  f32x4 accS[2];
  {
    const float ci = (m < 4) ? cb[b * 4 + m] : 0.f;
#pragma unroll
    for (int t = 0; t < 2; ++t) { accS[t][0] = ci; accS[t][1] = ci; accS[t][2] = ci; accS[t][3] = ci; }
#pragma unroll
    for (int t = 0; t < 2; ++t) {
      const int pos = (wave * 2 + t) * 16 + m;   // A row (position in tile)
#pragma unroll
      for (int s3 = 0; s3 < 3; ++s3) {
        u32 aw[4];
        if (s3 == 2 && q >= 2) {
          aw[0] = aw[1] = aw[2] = aw[3] = 0u;
        } else {
#pragma unroll
          for (int jp = 0; jp < 4; ++jp) {
            const int c0 = s3 * 32 + q * 8 + jp * 2;
            const int ps = pos ^ swz(c0);        // c0,c0+1 share (c>>3)
            u32 lo = smem[FT_BASE + c0 * FT_ST + ps];
            u32 hi = smem[FT_BASE + (c0 + 1) * FT_ST + ps];
            aw[jp] = lo | (hi << 16);
          }
        }
        accS[t] = __builtin_amdgcn_mfma_f32_16x16x32_bf16(*(const bf16x8*)aw, bfr[s3], accS[t], 0, 0, 0);
      }
    }
  }
  // wave max per head (D col m<4), reduce over q
  {
    float mx = accS[0][0];
#pragma unroll
    for (int t = 0; t < 2; ++t)
#pragma unroll
      for (int r = 0; r < 4; ++r) mx = fmaxf(mx, accS[t][r]);
    mx = fmaxf(mx, __shfl_xor(mx, 16, 64));
    mx = fmaxf(mx, __shfl_xor(mx, 32, 64));
    if (lane < 4) redf[wave * 4 + lane] = mx;
  }
  __syncthreads();   // B2: redf ready

  float bmv;
  {
    const int hh = m & 3;
    bmv = fmaxf(fmaxf(redf[hh], redf[4 + hh]), fmaxf(redf[8 + hh], redf[12 + hh]));
  }
  // exp (bf16-rounded), es_t write (cols m<4 -> head rows), wave sum
  {
    float ss = 0.f;
#pragma unroll
    for (int t = 0; t < 2; ++t) {
      const int T = wave * 2 + t;
#pragma unroll
      for (int r = 0; r < 4; ++r) {
        float e = __expf(accS[t][r] - bmv);
        u32 eb = f2bf(e);
        ss += bf2f((u16)eb);
        if (m < 4) smem[EST_BASE + m * FT_ST + T * 16 + q * 4 + r] = (u16)eb;
      }
    }
    ss += __shfl_xor(ss, 16, 64);
    ss += __shfl_xor(ss, 32, 64);
    if (lane < 4) red2f[wave * 4 + lane] = ss;
  }
  __syncthreads();   // B3: es_t + red2f ready

  if (tid < 4) {
    const int hh = tid;
    m_blk[bs * 4 + hh] = fmaxf(fmaxf(redf[hh], redf[4 + hh]), fmaxf(redf[8 + hh], redf[12 + hh]));
    sum_blk[bs * 4 + hh] = red2f[hh] + red2f[4 + hh] + red2f[8 + hh] + red2f[12 + hh];
  }
  // e_buf copy (bf16), layout [b][n][p]
  {
    const int n = tid >> 6, pp = tid & 63;
    u32 v = *(const u32*)&smem[EST_BASE + n * FT_ST + pp * 2];
    ((u32*)e_buf)[((size_t)(b * 4 + n)) * 2048 + s * 64 + pp] = v;
  }
  // pool MFMA: D[heads x 80ch] = es_t[16x128] @ featT^T, K split across waves
  // (es_t rows 4..15 are garbage; they only feed D rows 4..15 which are never read)
  {
    bf16x8 ap = *(const bf16x8*)&smem[EST_BASE + m * FT_ST + wave * 32 + q * 8];
    f32x4 accP[5];
#pragma unroll
    for (int T = 0; T < 5; ++T) { accP[T][0] = 0; accP[T][1] = 0; accP[T][2] = 0; accP[T][3] = 0; }
#pragma unroll
    for (int T = 0; T < 5; ++T) {
      const int c = T * 16 + m;                       // B row = channel
      const int g = (wave * 32 + q * 8) ^ swz(c);     // swizzled 8-pos group (16B aligned)
      bf16x8 bp = *(const bf16x8*)&smem[FT_BASE + c * FT_ST + g];
      accP[T] = __builtin_amdgcn_mfma_f32_16x16x32_bf16(ap, bp, accP[T], 0, 0, 0);
    }
    if (lane < 16) {   // D rows 0..3 (heads) live in q=0 lanes, regs 0..3
      float* pr = (float*)(smem + PR_BASE);
#pragma unroll
      for (int T = 0; T < 5; ++T)
#pragma unroll
        for (int r = 0; r < 4; ++r)
          pr[((wave * 5 + T) * 4 + r) * 16 + lane] = accP[T][r];
    }
  }
  __syncthreads();   // B4: poolred ready
  {
    const float* pr = (const float*)(smem + PR_BASE);
    for (int t = tid; t < 320; t += 256) {
      const int n = t / 80, c = t - n * 80;
      const int tile = c >> 4, cc = c & 15;
      float a = 0.f;
#pragma unroll
      for (int w = 0; w < 4; ++w) a += pr[((w * 5 + tile) * 4 + n) * 16 + cc];
      fpool_part[(size_t)bs * 320 + t] = a;
    }
  }
}

// ---------------- K34: escale; mean_attn; (s==0) pooled GEMV + extra ----------------
template<bool F32>
__device__ void k34_body(const float* m_blk, const float* sum_blk, const u16* e_buf,
                         const float* fpool_part, const void* Wv, const void* bv,
                         const void* extra, void* out, float* esc, float* fp) {
  const int tid = threadIdx.x;
  const int b = blockIdx.x & 63, s16 = blockIdx.x >> 6;
  if (tid < 4) {
    float M = -3.4e38f;
#pragma unroll
    for (int sp = 0; sp < NS; ++sp) M = fmaxf(M, m_blk[(b * NS + sp) * 4 + tid]);
    float den = 0.f;
#pragma unroll
    for (int sp = 0; sp < NS; ++sp)
      den += __expf(m_blk[(b * NS + sp) * 4 + tid] - M) * sum_blk[(b * NS + sp) * 4 + tid];
    float rd = 1.0f / den;
#pragma unroll
    for (int sp = 0; sp < NS; ++sp)
      esc[sp * 4 + tid] = __expf(m_blk[(b * NS + sp) * 4 + tid] - M) * rd;
  }
  __syncthreads();
  {
    const int gpos = s16 * 256 + tid;
    const int s32 = gpos >> 7;
    float mean = 0.f;
#pragma unroll
    for (int n = 0; n < 4; ++n)
      mean += bf2f(e_buf[(size_t)(b * 4 + n) * HW + gpos]) * esc[s32 * 4 + n];
    st<F32>(out, (size_t)BATCH * 320 + (size_t)b * HW + gpos, 0.25f * mean);
  }
  if (s16 == 0) {
    for (int idx = tid; idx < 320; idx += 256) {
      const int n2 = idx / 80;
      float a = 0.f;
#pragma unroll
      for (int sp = 0; sp < NS; ++sp)
        a += esc[sp * 4 + n2] * fpool_part[(size_t)(b * NS + sp) * 320 + idx];
      fp[idx] = a;
    }
    __syncthreads();
    if (tid < 64) {
      const int n = tid >> 4;
      float dot = 0.f;
#pragma unroll
      for (int c = 0; c < 80; ++c) dot += fp[n * 80 + c] * ld<F32>(Wv, (size_t)c * 64 + tid);
      st<F32>(out, (size_t)b * 320 + tid, dot + ld<F32>(bv, tid));
    }
    st<F32>(out, (size_t)b * 320 + 64 + tid, ld<F32>(extra, (size_t)b * 256 + tid));
  }
}

__global__ __launch_bounds__(256) void k34_out(
    const void* image, const float* m_blk, const float* sum_blk, const u16* e_buf,
    const float* fpool_part, const void* Wv, const void* bv, const void* extra, void* out) {
  __shared__ float esc[NS * 4];
  __shared__ float fp[320];
  if (detect_f32((const u16*)image))
       k34_body<true >(m_blk, sum_blk, e_buf, fpool_part, Wv, bv, extra, out, esc, fp);
  else k34_body<false>(m_blk, sum_blk, e_buf, fpool_part, Wv, bv, extra, out, esc, fp);
}

extern "C" void kernel_launch(void* const* d_in, const int* in_sizes, int n_in,
                              void* d_out, int out_size, void* d_ws, size_t ws_size,
                              hipStream_t stream) {
  (void)in_sizes; (void)n_in; (void)out_size; (void)ws_size;
  const void* image  = d_in[0];
  const void* state1 = d_in[1];
  const void* state2 = d_in[2];
  const void* extra  = d_in[3];
  const void* Wq = d_in[4];
  const void* bq = d_in[5];
  const void* Wk = d_in[6];
  const void* bk = d_in[7];
  const void* Wv = d_in[8];
  const void* bv = d_in[9];
  const void* basis = d_in[10];

  float* ws         = (float*)d_ws;
  float* cb         = ws;                    // 256
  float* m_blk      = ws + 256;              // 64*32*4 = 8192
  float* sum_blk    = ws + 8448;             // 8192
  float* fpool_part = ws + 16640;            // 2048*320 = 655360
  u16*   weffbt     = (u16*)(ws + 672000);   // 64*16*104 u16 = 106496
  u16*   e_buf      = (u16*)(ws + 725248);   // 64*4*4096 u16 (bf16)

  k1_prep<<<dim3(BATCH), dim3(256), 0, stream>>>(image, state1, state2, Wq, bq, Wk, bk, weffbt, cb);
  k2_main<<<dim3(BATCH * NS), dim3(256), 0, stream>>>(image, basis, cb, weffbt,
                                                      e_buf, m_blk, sum_blk, fpool_part);
  k34_out<<<dim3(BATCH * 16), dim3(256), 0, stream>>>(image, m_blk, sum_blk, e_buf,
                                                      fpool_part, Wv, bv, extra, d_out);
}

// Round 10
// 130.796 us; speedup vs baseline: 1.0665x; 1.0067x over previous
//
#include <hip/hip_runtime.h>
#include <hip/hip_bf16.h>

#define BATCH 64
#define HW    4096
#define PT    128      // positions per k2 tile
#define NS    32       // HW / PT
#define FT_ST 136      // es_t row stride in u16 (128 pos + 8 pad)
#define CP_ST 132      // cpi row stride in u32 (128 pos + 4 pad)

// LDS map for k2:
//   u32  [0..5280)      cpi [40][132]  (channel-pair-interleaved, pos-swizzled)
//   u16  [10560..12736) es_t [16][136] (rows 0..3 = heads; 4..15 garbage-ok)
//   u16  [12736..15296) poolred 1280 f32
//   u16  [15296..15360) redf 16 f32 + red2f 16 f32
#define EST_BASE 10560
#define PR_BASE  12736
#define RED_BASE 15296
#define SMEM_U32 7680    // 30720 B -> 4 blocks/CU

typedef unsigned int u32;
typedef unsigned short u16;
typedef __attribute__((ext_vector_type(8))) short bf16x8;
typedef __attribute__((ext_vector_type(4))) float f32x4;

__device__ __forceinline__ float bf2f(u16 h) { return __uint_as_float(((u32)h) << 16); }
__device__ __forceinline__ u32 f2bf(float x) {
  u32 b = __float_as_uint(x);
  return (b + 0x7fffu + ((b >> 16) & 1u)) >> 16;
}
// RNE pack of two floats to bf16x2 (lowers to v_cvt_pk_bf16_f32 where available)
__device__ __forceinline__ u32 pk2(float lo, float hi) {
  __hip_bfloat162 h = __float22bfloat162_rn(make_float2(lo, hi));
  u32 r; __builtin_memcpy(&r, &h, 4); return r;
}

template<bool F32>
__device__ __forceinline__ float ld(const void* p, size_t i) {
  if (F32) return ((const float*)p)[i];
  return bf2f(((const u16*)p)[i]);
}
template<bool F32>
__device__ __forceinline__ void st(void* p, size_t i, float v) {
  if (F32) ((float*)p)[i] = v;
  else     ((__hip_bfloat16*)p)[i] = __float2bfloat16(v);
}

// Per-wave dtype sniff (block-uniform; same 128B every wave -> L2 broadcast).
__device__ __forceinline__ bool detect_f32(const u16* __restrict__ image) {
  u16 h = image[(threadIdx.x & 63) * 2];
  u32 e = (h >> 7) & 0xFFu;
  unsigned long long m = __ballot(e >= 0x86u);
  return __popcll(m) >= 8;
}

// position swizzle for cpi row r: XOR pos bits 3..4 with (r>>2)&3
__device__ __forceinline__ int swr(int r) { return ((r >> 2) & 3) << 3; }

// ---------------- K1: q = state@Wq+bq; weffbt (bf16 [n][104] zero-padded); cb ----------------
template<bool F32>
__device__ void k1_body(const void* state1, const void* state2, const void* Wq, const void* bq,
                        const void* Wk, const void* bk, u16* weffbt, float* cb,
                        float* stt, float* qp, float* q) {
  const int b = blockIdx.x, tid = threadIdx.x;
  for (int i = tid; i < 512; i += 256) {
    stt[i]       = ld<F32>(state1, (size_t)b * 512 + i);
    stt[512 + i] = ld<F32>(state2, (size_t)b * 512 + i);
  }
  u32* wz = (u32*)(weffbt + (size_t)b * 1664);
  for (int i = tid; i < 832; i += 256) wz[i] = 0u;
  __syncthreads();
  {
    const int j = tid & 63, g = tid >> 6, i0 = g * 256;
    float a = 0.f;
#pragma unroll 8
    for (int i = 0; i < 256; ++i) a += stt[i0 + i] * ld<F32>(Wq, (size_t)(i0 + i) * 64 + j);
    qp[g * 64 + j] = a;
  }
  __syncthreads();
  if (tid < 64) q[tid] = qp[tid] + qp[64 + tid] + qp[128 + tid] + qp[192 + tid] + ld<F32>(bq, tid);
  __syncthreads();
  for (int t = tid; t < 320; t += 256) {
    const int c = t >> 2, n = t & 3;
    float a = 0.f;
#pragma unroll
    for (int d = 0; d < 16; ++d) a += ld<F32>(Wk, (size_t)c * 64 + n * 16 + d) * q[n * 16 + d];
    weffbt[(size_t)b * 1664 + n * 104 + c] = (u16)f2bf(a);
  }
  if (tid < 4) {
    float a = 0.f;
#pragma unroll
    for (int d = 0; d < 16; ++d) a += ld<F32>(bk, tid * 16 + d) * q[tid * 16 + d];
    cb[b * 4 + tid] = a;
  }
}

__global__ __launch_bounds__(256) void k1_prep(
    const void* image, const void* state1, const void* state2, const void* Wq, const void* bq,
    const void* Wk, const void* bk, u16* weffbt, float* cb) {
  __shared__ float stt[1024];
  __shared__ float qp[256];
  __shared__ float q[64];
  if (detect_f32((const u16*)image))
       k1_body<true >(state1, state2, Wq, bq, Wk, bk, weffbt, cb, stt, qp, q);
  else k1_body<false>(state1, state2, Wq, bq, Wk, bk, weffbt, cb, stt, qp, q);
}

// ---------------- K2: cpi staging; MFMA score (direct b32 A-frags) + MFMA pool (perm) ----------------
__global__ __launch_bounds__(256, 4) void k2_main(
    const void* __restrict__ image, const void* __restrict__ basis,
    const float* __restrict__ cb, const u16* __restrict__ weffbt,
    u16* __restrict__ e_buf, float* __restrict__ m_blk, float* __restrict__ sum_blk,
    float* __restrict__ fpool_part) {
  __shared__ __align__(16) u32 smem32[SMEM_U32];
  u16* smem = (u16*)smem32;
  u32* cpi = smem32;
  float* redf  = (float*)(smem + RED_BASE);
  float* red2f = (float*)(smem + RED_BASE + 32);

  const int tid = threadIdx.x;
  const int b = blockIdx.x & 63, s = blockIdx.x >> 6;
  const int bs = b * NS + s;
  const int wave = tid >> 6, lane = tid & 63;
  const int m = lane & 15, q = lane >> 4;
  const bool isf32 = detect_f32((const u16*)image);

  // ---- stage cpi: row r holds (bf16 ch2r, bf16 ch2r+1) per position ----
  if (isf32) {
    const float4* img4 = (const float4*)image + ((size_t)(b * HW + s * PT)) * 16;
#pragma unroll
    for (int i = 0; i < 8; ++i) {
      const int fidx = i * 256 + tid;          // 0..2047: (pos, c4)
      const int p = fidx >> 4, c4 = fidx & 15;
      float4 v = img4[fidx];
      const int r0 = c4 * 2, sw = swr(r0);     // r0, r0+1 share (r>>2)
      cpi[r0 * CP_ST + (p ^ sw)]        = pk2(v.x, v.y);
      cpi[(r0 + 1) * CP_ST + (p ^ sw)]  = pk2(v.z, v.w);
    }
    const float4* bas4 = (const float4*)basis + (size_t)(s * PT) * 4;
#pragma unroll
    for (int i = 0; i < 2; ++i) {
      const int fidx = i * 256 + tid;          // 0..511: (pos, c4)
      const int p = fidx >> 2, c4 = fidx & 3;
      float4 v = bas4[fidx];
      const int r0 = 32 + c4 * 2, sw = swr(r0);
      cpi[r0 * CP_ST + (p ^ sw)]        = pk2(v.x, v.y);
      cpi[(r0 + 1) * CP_ST + (p ^ sw)]  = pk2(v.z, v.w);
    }
  } else {
    const uint4* img4 = (const uint4*)image + ((size_t)(b * HW + s * PT)) * 8;
#pragma unroll
    for (int i = 0; i < 4; ++i) {
      const int fidx = i * 256 + tid;          // 0..1023: (pos, c8)
      const int p = fidx >> 3, c8 = fidx & 7;
      uint4 u = img4[fidx];
      const int rb = c8 * 4;                   // rows rb..rb+3 share (r>>2)=c8
      const int base = rb * CP_ST + (p ^ swr(rb));
      cpi[base]              = u.x;
      cpi[base + CP_ST]      = u.y;
      cpi[base + 2 * CP_ST]  = u.z;
      cpi[base + 3 * CP_ST]  = u.w;
    }
    const uint4* bas4 = (const uint4*)basis + (size_t)(s * PT) * 2;
    {
      const int p = tid >> 1, c8 = tid & 1;    // 256 uint4
      uint4 u = bas4[tid];
      const int rb = 32 + c8 * 4;
      const int base = rb * CP_ST + (p ^ swr(rb));
      cpi[base]              = u.x;
      cpi[base + CP_ST]      = u.y;
      cpi[base + 2 * CP_ST]  = u.z;
      cpi[base + 3 * CP_ST]  = u.w;
    }
  }
  // score B-frags from global (per-lane, L2-hot, no barrier dependency)
  bf16x8 bfr[3];
  {
    const u16* wrow = weffbt + (size_t)b * 1664 + m * 104;
#pragma unroll
    for (int s3 = 0; s3 < 3; ++s3) bfr[s3] = *(const bf16x8*)&wrow[s3 * 32 + q * 8];
  }
  __syncthreads();   // B1: cpi staged

  // ---- score MFMA: A-frags direct from cpi (row r = chan pair, swizzle = q<<3) ----
  f32x4 accS[2];
  {
    const float ci = (m < 4) ? cb[b * 4 + m] : 0.f;
#pragma unroll
    for (int t = 0; t < 2; ++t) { accS[t][0] = ci; accS[t][1] = ci; accS[t][2] = ci; accS[t][3] = ci; }
#pragma unroll
    for (int t = 0; t < 2; ++t) {
      const int pos = (wave * 2 + t) * 16 + m;     // A row (position in tile)
      const int psw = pos ^ (q << 3);              // (r>>2)&3 == q for all score rows
#pragma unroll
      for (int s3 = 0; s3 < 3; ++s3) {
        u32 aw[4];
        if (s3 == 2 && q >= 2) {
          aw[0] = aw[1] = aw[2] = aw[3] = 0u;
        } else {
          const int rbase = s3 * 16 + q * 4;
#pragma unroll
          for (int jp = 0; jp < 4; ++jp) aw[jp] = cpi[(rbase + jp) * CP_ST + psw];
        }
        accS[t] = __builtin_amdgcn_mfma_f32_16x16x32_bf16(*(const bf16x8*)aw, bfr[s3], accS[t], 0, 0, 0);
      }
    }
  }
  // wave max per head (D col m<4), reduce over q
  {
    float mx = accS[0][0];
#pragma unroll
    for (int t = 0; t < 2; ++t)
#pragma unroll
      for (int r = 0; r < 4; ++r) mx = fmaxf(mx, accS[t][r]);
    mx = fmaxf(mx, __shfl_xor(mx, 16, 64));
    mx = fmaxf(mx, __shfl_xor(mx, 32, 64));
    if (lane < 4) redf[wave * 4 + lane] = mx;
  }
  __syncthreads();   // B2: redf ready

  float bmv;
  {
    const int hh = m & 3;
    bmv = fmaxf(fmaxf(redf[hh], redf[4 + hh]), fmaxf(redf[8 + hh], redf[12 + hh]));
  }
  // exp (bf16-rounded), es_t write (cols m<4 -> head rows), wave sum
  {
    float ss = 0.f;
#pragma unroll
    for (int t = 0; t < 2; ++t) {
      const int T = wave * 2 + t;
#pragma unroll
      for (int r = 0; r < 4; ++r) {
        float e = __expf(accS[t][r] - bmv);
        u32 eb = f2bf(e);
        ss += bf2f((u16)eb);
        if (m < 4) smem[EST_BASE + m * FT_ST + T * 16 + q * 4 + r] = (u16)eb;
      }
    }
    ss += __shfl_xor(ss, 16, 64);
    ss += __shfl_xor(ss, 32, 64);
    if (lane < 4) red2f[wave * 4 + lane] = ss;
  }
  __syncthreads();   // B3: es_t + red2f ready

  if (tid < 4) {
    const int hh = tid;
    m_blk[bs * 4 + hh] = fmaxf(fmaxf(redf[hh], redf[4 + hh]), fmaxf(redf[8 + hh], redf[12 + hh]));
    sum_blk[bs * 4 + hh] = red2f[hh] + red2f[4 + hh] + red2f[8 + hh] + red2f[12 + hh];
  }
  // e_buf copy (bf16), layout [b][n][p]
  {
    const int n = tid >> 6, pp = tid & 63;
    u32 v = *(const u32*)&smem[EST_BASE + n * FT_ST + pp * 2];
    ((u32*)e_buf)[((size_t)(b * 4 + n)) * 2048 + s * 64 + pp] = v;
  }
  // pool MFMA: D[heads x 80ch] = es_t[16x128] @ featT^T; B-frags from cpi via v_perm
  {
    bf16x8 ap = *(const bf16x8*)&smem[EST_BASE + m * FT_ST + wave * 32 + q * 8];
    f32x4 accP[5];
#pragma unroll
    for (int T = 0; T < 5; ++T) { accP[T][0] = 0; accP[T][1] = 0; accP[T][2] = 0; accP[T][3] = 0; }
#pragma unroll
    for (int T = 0; T < 5; ++T) {
      const int c = T * 16 + m;                      // B row = channel
      const int r = c >> 1;
      const u32 sel = (c & 1) ? 0x07060302u : 0x05040100u;
      const int p0 = (wave * 32 + q * 8) ^ swr(r);   // swizzled 8-pos run (16B aligned)
      const uint4* w01 = (const uint4*)&cpi[r * CP_ST + p0];
      uint4 wa = w01[0], wb = w01[1];
      u32 bw[4];
      bw[0] = __builtin_amdgcn_perm(wa.y, wa.x, sel);
      bw[1] = __builtin_amdgcn_perm(wa.w, wa.z, sel);
      bw[2] = __builtin_amdgcn_perm(wb.y, wb.x, sel);
      bw[3] = __builtin_amdgcn_perm(wb.w, wb.z, sel);
      accP[T] = __builtin_amdgcn_mfma_f32_16x16x32_bf16(ap, *(const bf16x8*)bw, accP[T], 0, 0, 0);
    }
    if (lane < 16) {   // D rows 0..3 (heads) live in q=0 lanes, regs 0..3
      float* pr = (float*)(smem + PR_BASE);
#pragma unroll
      for (int T = 0; T < 5; ++T)
#pragma unroll
        for (int r = 0; r < 4; ++r)
          pr[((wave * 5 + T) * 4 + r) * 16 + lane] = accP[T][r];
    }
  }
  __syncthreads();   // B4: poolred ready
  {
    const float* pr = (const float*)(smem + PR_BASE);
    for (int t = tid; t < 320; t += 256) {
      const int n = t / 80, c = t - n * 80;
      const int tile = c >> 4, cc = c & 15;
      float a = 0.f;
#pragma unroll
      for (int w = 0; w < 4; ++w) a += pr[((w * 5 + tile) * 4 + n) * 16 + cc];
      fpool_part[(size_t)bs * 320 + t] = a;
    }
  }
}

// ---------------- K34: escale; mean_attn; (s==0) pooled GEMV + extra ----------------
template<bool F32>
__device__ void k34_body(const float* m_blk, const float* sum_blk, const u16* e_buf,
                         const float* fpool_part, const void* Wv, const void* bv,
                         const void* extra, void* out, float* esc, float* fp) {
  const int tid = threadIdx.x;
  const int b = blockIdx.x & 63, s16 = blockIdx.x >> 6;
  if (tid < 4) {
    float M = -3.4e38f;
#pragma unroll
    for (int sp = 0; sp < NS; ++sp) M = fmaxf(M, m_blk[(b * NS + sp) * 4 + tid]);
    float den = 0.f;
#pragma unroll
    for (int sp = 0; sp < NS; ++sp)
      den += __expf(m_blk[(b * NS + sp) * 4 + tid] - M) * sum_blk[(b * NS + sp) * 4 + tid];
    float rd = 1.0f / den;
#pragma unroll
    for (int sp = 0; sp < NS; ++sp)
      esc[sp * 4 + tid] = __expf(m_blk[(b * NS + sp) * 4 + tid] - M) * rd;
  }
  __syncthreads();
  {
    const int gpos = s16 * 256 + tid;
    const int s32 = gpos >> 7;
    float mean = 0.f;
#pragma unroll
    for (int n = 0; n < 4; ++n)
      mean += bf2f(e_buf[(size_t)(b * 4 + n) * HW + gpos]) * esc[s32 * 4 + n];
    st<F32>(out, (size_t)BATCH * 320 + (size_t)b * HW + gpos, 0.25f * mean);
  }
  if (s16 == 0) {
    for (int idx = tid; idx < 320; idx += 256) {
      const int n2 = idx / 80;
      float a = 0.f;
#pragma unroll
      for (int sp = 0; sp < NS; ++sp)
        a += esc[sp * 4 + n2] * fpool_part[(size_t)(b * NS + sp) * 320 + idx];
      fp[idx] = a;
    }
    __syncthreads();
    if (tid < 64) {
      const int n = tid >> 4;
      float dot = 0.f;
#pragma unroll
      for (int c = 0; c < 80; ++c) dot += fp[n * 80 + c] * ld<F32>(Wv, (size_t)c * 64 + tid);
      st<F32>(out, (size_t)b * 320 + tid, dot + ld<F32>(bv, tid));
    }
    st<F32>(out, (size_t)b * 320 + 64 + tid, ld<F32>(extra, (size_t)b * 256 + tid));
  }
}

__global__ __launch_bounds__(256) void k34_out(
    const void* image, const float* m_blk, const float* sum_blk, const u16* e_buf,
    const float* fpool_part, const void* Wv, const void* bv, const void* extra, void* out) {
  __shared__ float esc[NS * 4];
  __shared__ float fp[320];
  if (detect_f32((const u16*)image))
       k34_body<true >(m_blk, sum_blk, e_buf, fpool_part, Wv, bv, extra, out, esc, fp);
  else k34_body<false>(m_blk, sum_blk, e_buf, fpool_part, Wv, bv, extra, out, esc, fp);
}

extern "C" void kernel_launch(void* const* d_in, const int* in_sizes, int n_in,
                              void* d_out, int out_size, void* d_ws, size_t ws_size,
                              hipStream_t stream) {
  (void)in_sizes; (void)n_in; (void)out_size; (void)ws_size;
  const void* image  = d_in[0];
  const void* state1 = d_in[1];
  const void* state2 = d_in[2];
  const void* extra  = d_in[3];
  const void* Wq = d_in[4];
  const void* bq = d_in[5];
  const void* Wk = d_in[6];
  const void* bk = d_in[7];
  const void* Wv = d_in[8];
  const void* bv = d_in[9];
  const void* basis = d_in[10];

  float* ws         = (float*)d_ws;
  float* cb         = ws;                    // 256
  float* m_blk      = ws + 256;              // 64*32*4 = 8192
  float* sum_blk    = ws + 8448;             // 8192
  float* fpool_part = ws + 16640;            // 2048*320 = 655360
  u16*   weffbt     = (u16*)(ws + 672000);   // 64*16*104 u16 = 106496
  u16*   e_buf      = (u16*)(ws + 725248);   // 64*4*4096 u16 (bf16)

  k1_prep<<<dim3(BATCH), dim3(256), 0, stream>>>(image, state1, state2, Wq, bq, Wk, bk, weffbt, cb);
  k2_main<<<dim3(BATCH * NS), dim3(256), 0, stream>>>(image, basis, cb, weffbt,
                                                      e_buf, m_blk, sum_blk, fpool_part);
  k34_out<<<dim3(BATCH * 16), dim3(256), 0, stream>>>(image, m_blk, sum_blk, e_buf,
                                                      fpool_part, Wv, bv, extra, d_out);
}